// Round 20
// baseline (113.259 us; speedup 1.0000x reference)
//
#include <hip/hip_runtime.h>
#include <hip/hip_bf16.h>

#define H_   4
#define D_   32
#define HD   128   // H*D
#define IND  128
#define OUTD 128
#define NET  3
#define NEG  0.2f
#define CAP  2048  // bucket capacity (expected ~819 edges/bucket, P(>2048) ~ 0)

typedef short short8 __attribute__((ext_vector_type(8)));
typedef float f32x4  __attribute__((ext_vector_type(4)));

#define AS_GLOBAL(p) ((const __attribute__((address_space(1))) unsigned int*)(p))
#define AS_LDS(p)    ((__attribute__((address_space(3))) unsigned int*)(p))

__device__ __forceinline__ unsigned short f2bf(float f) {
  union { __hip_bfloat16 b; unsigned short u; } x;
  x.b = __float2bfloat16(f);
  return x.u;
}

__device__ __forceinline__ short8 pack_bf8(float4 lo, float4 hi) {
  union { short8 s; unsigned short u[8]; } r;
  r.u[0] = f2bf(lo.x); r.u[1] = f2bf(lo.y); r.u[2] = f2bf(lo.z); r.u[3] = f2bf(lo.w);
  r.u[4] = f2bf(hi.x); r.u[5] = f2bf(hi.y); r.u[6] = f2bf(hi.z); r.u[7] = f2bf(hi.w);
  return r.s;
}

#define BFLO(x) __uint_as_float((x) << 16)
#define BFHI(x) __uint_as_float((x) & 0xFFFF0000u)

// ---------------- K0b: pre-swizzled bf16 weight panels + inline Wred + gbuck zero ----------------
__global__ void k0b_pack(const float* __restrict__ Wq, const float* __restrict__ Wk,
                         const float* __restrict__ attn, const float* __restrict__ ee,
                         const float* __restrict__ Wv, const float* __restrict__ Wout,
                         unsigned short* __restrict__ Wallt,
                         unsigned short* __restrict__ Woutt,
                         int* __restrict__ gbuck, int nbuck) {
  int b = blockIdx.x, i = threadIdx.x; // i = K index
  if (b == 288) {
    for (int k = i; k < nbuck; k += 128) gbuck[k] = 0;  // replaces hipMemsetAsync
    return;
  }
  if (b < 160) {
    int c = b;
    float val = 0.f;
    if (c < 128) {
      val = Wv[i*HD + c];
    } else {
      int cc = c - 128;
      if (cc < 4) {                      // sq(h)
        int h = cc;
        for (int d = 0; d < D_; d++) val += Wq[i*HD + h*D_ + d] * attn[h*2*D_ + d];
      } else if (cc < 16) {              // qe(t,h)
        int t2 = (cc - 4) >> 2, h = (cc - 4) & 3;
        for (int d = 0; d < D_; d++) val += Wq[i*HD + h*D_ + d] * ee[t2*HD + h*D_ + d];
      } else if (cc < 20) {              // sk(h)
        int h = cc - 16;
        for (int d = 0; d < D_; d++) val += Wk[i*HD + h*D_ + d] * attn[h*2*D_ + D_ + d];
      }
    }
    Wallt[(c*128 + i) ^ ((c & 7) << 3)] = f2bf(val);
  } else {
    int c = b - 160;
    Woutt[(c*128 + i) ^ ((c & 7) << 3)] = f2bf(Wout[i*OUTD + c]);
  }
}

// ---------------- K1B: grid-split kernel — bucket blocks FIRST (nbb=64), then GEMM ----------------
// nbb=64: per-(block,bucket) run = ~12.8 edges = ~51B -> ebuf writes ~1 line/run
// (vs 5x amplification at nbb=256); 50K reservation atomics. Bucket work fully
// overlaps the 1563-block GEMM wave.
__global__ __launch_bounds__(256) void k1b(const float* __restrict__ x,
    const uint4* __restrict__ Wallt,
    unsigned short* __restrict__ vb, unsigned short* __restrict__ nqb,
    float* __restrict__ skb, int n, int nbb,
    const int* __restrict__ ei, const int* __restrict__ et,
    int* __restrict__ gbuck, unsigned int* __restrict__ ebuf,
    int E_, int nbuck, int per) {
  extern __shared__ char dlds[];
  int t = threadIdx.x;
  if (blockIdx.x < nbb) {
    // ---- bucket part ----
    int* cnt  = (int*)dlds;
    int* base = cnt + 1024;
    for (int i = t; i < nbuck; i += 256) cnt[i] = 0;
    __syncthreads();
    int bb = blockIdx.x;
    int e0 = bb * per;
    int e1 = min(e0 + per, E_);
    for (int e = e0 + t; e < e1; e += 256)
      atomicAdd(&cnt[ei[E_ + e] >> 7], 1);
    __syncthreads();
    for (int i = t; i < nbuck; i += 256) {
      int c = cnt[i];
      base[i] = c ? atomicAdd(&gbuck[i], c) : 0;
      cnt[i] = 0;
    }
    __syncthreads();
    for (int e = e0 + t; e < e1; e += 256) {
      int d = ei[E_ + e];
      int b = d >> 7;
      int pos = base[b] + atomicAdd(&cnt[b], 1);
      ebuf[(size_t)b * CAP + pos] =
          (unsigned)ei[e] | ((unsigned)et[e] << 17) | ((unsigned)(d & 127) << 19);
    }
    return;
  }
  // ---- GEMM part ----
  uint4* ldsB = (uint4*)dlds;
  int wv = t >> 6, lane = t & 63;
  int l15 = lane & 15, l16 = lane >> 4;
  int base = (blockIdx.x - nbb) * 64;
  int arow = base + wv*16 + l15;
  int rr = min(arow, n - 1);
  const float* xr = &x[(size_t)rr*IND + l16*8];
  float4 lo[4], hi[4];
  #pragma unroll
  for (int kk = 0; kk < 4; kk++) {
    lo[kk] = *(const float4*)(xr + kk*32);
    hi[kk] = *(const float4*)(xr + kk*32 + 4);
  }
  #pragma unroll
  for (int i = 0; i < 10; i++) {
    const uint4* gp = Wallt + i*256 + wv*64 + lane;
    uint4* lp = (uint4*)dlds + i*256 + wv*64;  // wave-uniform; HW adds lane*16
    __builtin_amdgcn_global_load_lds(AS_GLOBAL(gp), AS_LDS(lp), 16, 0, 0);
  }
  short8 afr[4];
  #pragma unroll
  for (int kk = 0; kk < 4; kk++) afr[kk] = pack_bf8(lo[kk], hi[kk]);
  __syncthreads();
  f32x4 acc[10];
  #pragma unroll
  for (int nt = 0; nt < 10; nt++) acc[nt] = (f32x4){0.f, 0.f, 0.f, 0.f};
  #pragma unroll
  for (int nt = 0; nt < 10; nt++) {
    int bcol = nt*16 + l15;
    #pragma unroll
    for (int kk = 0; kk < 4; kk++) {
      int bytec = kk*64 + l16*16;
      short8 b = *(const short8*)((const char*)ldsB + ((bcol*256 + bytec) ^ ((bcol & 7) << 4)));
      acc[nt] = __builtin_amdgcn_mfma_f32_16x16x32_bf16(afr[kk], b, acc[nt], 0, 0, 0);
    }
  }
  int rowbase = base + wv*16 + l16*4;
  #pragma unroll
  for (int nt = 0; nt < 10; nt++) {
    int col = nt*16 + l15;
    #pragma unroll
    for (int r = 0; r < 4; r++) {
      int row = rowbase + r;
      if (row >= n) continue;
      float val = acc[nt][r];
      if (nt < 8)       vb[(size_t)row*HD + col] = f2bf(val);
      else if (nt == 8) nqb[((size_t)row << 4) + (col - 128)] = f2bf(val);
      else { int c = col - 144; if (c < 4) skb[(size_t)row*4 + c] = val; }
    }
  }
}

// ---------------- K3F: fused per-bucket counting sort (LDS) + softmax-aggregation ----------------
// TWO blocks per bucket (measured-best): both sort the full bucket into LDS;
// each block gathers 64 of the 128 dsts.
__global__ __launch_bounds__(256) void k3f(const unsigned int* __restrict__ ebuf,
    const int* __restrict__ gbuck,
    const unsigned short* __restrict__ nqb, const float* __restrict__ skb,
    const unsigned short* __restrict__ vb, unsigned short* __restrict__ aggb, int n) {
  __shared__ unsigned int el[CAP];     // 8KB sorted edge words
  __shared__ int cnt[128], cur[128], sc[128];
  __shared__ float s_esc[16][17][4];
  __shared__ int s_src[16][17];
  int b = blockIdx.x >> 1;
  int half = blockIdx.x & 1;
  int t = threadIdx.x;
  int m = gbuck[b];
  if (t < 128) cnt[t] = 0;
  __syncthreads();
  const unsigned int* eb = ebuf + (size_t)b * CAP;
  for (int i = t; i < m; i += 256)
    atomicAdd(&cnt[(eb[i] >> 19) & 127], 1);
  __syncthreads();
  if (t < 128) sc[t] = cnt[t];
  __syncthreads();
  for (int off = 1; off < 128; off <<= 1) {
    int v = (t >= off && t < 128) ? sc[t - off] : 0;
    __syncthreads();
    if (t < 128) sc[t] += v;
    __syncthreads();
  }
  if (t < 128) cur[t] = sc[t] - cnt[t];
  __syncthreads();
  for (int i = t; i < m; i += 256) {
    unsigned int w = eb[i];
    int dl = (w >> 19) & 127;
    el[atomicAdd(&cur[dl], 1)] = w;
  }
  __syncthreads();
  // ---- gather phase: group g handles dsts dl = half*64 + g*4 .. +3 ----
  int g = t >> 4, s = t & 15;
  int h = s >> 2;
  for (int k = 0; k < 4; k++) {
    int dl = half*64 + g*4 + k;
    int dst = b*128 + dl;
    if (dst >= n) continue;
    int deg = cnt[dl];
    unsigned short* orow = &aggb[(size_t)dst*HD + s*8];
    if (deg == 0) {
      *(uint4*)orow = make_uint4(0u, 0u, 0u, 0u);
      continue;
    }
    int off0 = sc[dl] - deg;
    float4 sk4 = *(const float4*)(&skb[(size_t)dst*4]);
    float dp0 = 0.f, dp1 = 0.f, dp2 = 0.f, dp3 = 0.f;
    float a0=0.f,a1=0.f,a2=0.f,a3=0.f,a4=0.f,a5=0.f,a6=0.f,a7=0.f;
    for (int bas = 0; bas < deg; bas += 16) {
      int cnt2 = min(16, deg - bas);
      float e0 = 0.f, e1 = 0.f, e2 = 0.f, e3 = 0.f;
      int srcoff = 0;
      if (s < cnt2) {
        unsigned int p = el[off0 + bas + s];
        int src = p & 0x1FFFF;
        int ety = (p >> 17) & 3;
        const unsigned short* nr = nqb + ((size_t)src << 4);
        uint2 sqp = *(const uint2*)nr;                 // sq[0..3] bf16
        uint2 qep = *(const uint2*)(nr + 4 + ety*4);   // qe[ety][0..3] bf16
        float s0 = BFLO(sqp.x) + sk4.x;
        float s1 = BFHI(sqp.x) + sk4.y;
        float s2 = BFLO(sqp.y) + sk4.z;
        float s3 = BFHI(sqp.y) + sk4.w;
        s0 = (s0 >= 0.f ? s0 : NEG*s0) + BFLO(qep.x); e0 = __expf(s0);
        s1 = (s1 >= 0.f ? s1 : NEG*s1) + BFHI(qep.x); e1 = __expf(s1);
        s2 = (s2 >= 0.f ? s2 : NEG*s2) + BFLO(qep.y); e2 = __expf(s2);
        s3 = (s3 >= 0.f ? s3 : NEG*s3) + BFHI(qep.y); e3 = __expf(s3);
        dp0 += e0; dp1 += e1; dp2 += e2; dp3 += e3;
        srcoff = src << 7;             // src*HD
      }
      s_src[g][s] = srcoff;
      *(float4*)(&s_esc[g][s][0]) = make_float4(e0, e1, e2, e3);
      __builtin_amdgcn_wave_barrier();
      int e = 0;
      for (; e + 4 <= cnt2; e += 4) {    // 4 gathers in flight per lane
        float al0 = s_esc[g][e+0][h], al1 = s_esc[g][e+1][h];
        float al2 = s_esc[g][e+2][h], al3 = s_esc[g][e+3][h];
        const unsigned short* p0 = vb + s_src[g][e+0] + s*8;
        const unsigned short* p1 = vb + s_src[g][e+1] + s*8;
        const unsigned short* p2 = vb + s_src[g][e+2] + s*8;
        const unsigned short* p3 = vb + s_src[g][e+3] + s*8;
        uint4 v0 = *(const uint4*)p0;
        uint4 v1 = *(const uint4*)p1;
        uint4 v2 = *(const uint4*)p2;
        uint4 v3 = *(const uint4*)p3;
        a0 += al0 * BFLO(v0.x); a1 += al0 * BFHI(v0.x);
        a2 += al0 * BFLO(v0.y); a3 += al0 * BFHI(v0.y);
        a4 += al0 * BFLO(v0.z); a5 += al0 * BFHI(v0.z);
        a6 += al0 * BFLO(v0.w); a7 += al0 * BFHI(v0.w);
        a0 += al1 * BFLO(v1.x); a1 += al1 * BFHI(v1.x);
        a2 += al1 * BFLO(v1.y); a3 += al1 * BFHI(v1.y);
        a4 += al1 * BFLO(v1.z); a5 += al1 * BFHI(v1.z);
        a6 += al1 * BFLO(v1.w); a7 += al1 * BFHI(v1.w);
        a0 += al2 * BFLO(v2.x); a1 += al2 * BFHI(v2.x);
        a2 += al2 * BFLO(v2.y); a3 += al2 * BFHI(v2.y);
        a4 += al2 * BFLO(v2.z); a5 += al2 * BFHI(v2.z);
        a6 += al2 * BFLO(v2.w); a7 += al2 * BFHI(v2.w);
        a0 += al3 * BFLO(v3.x); a1 += al3 * BFHI(v3.x);
        a2 += al3 * BFLO(v3.y); a3 += al3 * BFHI(v3.y);
        a4 += al3 * BFLO(v3.z); a5 += al3 * BFHI(v3.z);
        a6 += al3 * BFLO(v3.w); a7 += al3 * BFHI(v3.w);
      }
      for (; e < cnt2; e++) {
        float a = s_esc[g][e][h];
        const unsigned short* p = vb + s_src[g][e] + s*8;
        uint4 vv = *(const uint4*)p;
        a0 += a * BFLO(vv.x); a1 += a * BFHI(vv.x);
        a2 += a * BFLO(vv.y); a3 += a * BFHI(vv.y);
        a4 += a * BFLO(vv.z); a5 += a * BFHI(vv.z);
        a6 += a * BFLO(vv.w); a7 += a * BFHI(vv.w);
      }
      __builtin_amdgcn_wave_barrier();
    }
    #pragma unroll
    for (int off = 1; off < 16; off <<= 1) {
      dp0 += __shfl_xor(dp0, off);
      dp1 += __shfl_xor(dp1, off);
      dp2 += __shfl_xor(dp2, off);
      dp3 += __shfl_xor(dp3, off);
    }
    float den = (h == 0) ? dp0 : (h == 1) ? dp1 : (h == 2) ? dp2 : dp3;
    float inv = 1.f / (den + 1e-10f);
    uint4 pk;
    pk.x = (unsigned)f2bf(a0*inv) | ((unsigned)f2bf(a1*inv) << 16);
    pk.y = (unsigned)f2bf(a2*inv) | ((unsigned)f2bf(a3*inv) << 16);
    pk.z = (unsigned)f2bf(a4*inv) | ((unsigned)f2bf(a5*inv) << 16);
    pk.w = (unsigned)f2bf(a6*inv) | ((unsigned)f2bf(a7*inv) << 16);
    *(uint4*)orow = pk;
  }
}

// ---------------- K4: MFMA GEMM  out = aggb @ Wout + bout ----------------
__global__ __launch_bounds__(256) void k4_gemm(const unsigned short* __restrict__ aggb,
    const uint4* __restrict__ Woutt, const float* __restrict__ bout,
    float* __restrict__ out, int n) {
  __shared__ uint4 ldsB[2048]; // 32KB
  int t = threadIdx.x;
  #pragma unroll
  for (int i = 0; i < 8; i++) ldsB[i*256 + t] = Woutt[i*256 + t];
  int wv = t >> 6, lane = t & 63;
  int l15 = lane & 15, l16 = lane >> 4;
  int base = blockIdx.x * 64;
  int arow = base + wv*16 + l15;
  int rr = min(arow, n - 1);
  const unsigned short* ar = &aggb[(size_t)rr*HD + l16*8];
  short8 afr[4];
  #pragma unroll
  for (int kk = 0; kk < 4; kk++)
    afr[kk] = *(const short8*)(ar + kk*32);
  __syncthreads();
  f32x4 acc[8];
  #pragma unroll
  for (int nt = 0; nt < 8; nt++) acc[nt] = (f32x4){0.f, 0.f, 0.f, 0.f};
  #pragma unroll
  for (int nt = 0; nt < 8; nt++) {
    int bcol = nt*16 + l15;
    #pragma unroll
    for (int kk = 0; kk < 4; kk++) {
      int bytec = kk*64 + l16*16;
      short8 b = *(const short8*)((const char*)ldsB + ((bcol*256 + bytec) ^ ((bcol & 7) << 4)));
      acc[nt] = __builtin_amdgcn_mfma_f32_16x16x32_bf16(afr[kk], b, acc[nt], 0, 0, 0);
    }
  }
  int rowbase = base + wv*16 + l16*4;
  #pragma unroll
  for (int nt = 0; nt < 8; nt++) {
    int col = nt*16 + l15;
    float bv = bout[col];
    #pragma unroll
    for (int r = 0; r < 4; r++) {
      int row = rowbase + r;
      if (row < n) out[(size_t)row*OUTD + col] = acc[nt][r] + bv;
    }
  }
}

extern "C" void kernel_launch(void* const* d_in, const int* in_sizes, int n_in,
                              void* d_out, int out_size, void* d_ws, size_t ws_size,
                              hipStream_t stream) {
  const float* x    = (const float*)d_in[0];
  const float* Wq   = (const float*)d_in[1];
  const float* Wk   = (const float*)d_in[2];
  const float* Wv   = (const float*)d_in[3];
  const float* attn = (const float*)d_in[4];
  const float* ee   = (const float*)d_in[5];
  const float* Wout = (const float*)d_in[6];
  const float* bout = (const float*)d_in[7];
  const int*   ei   = (const int*)d_in[8];
  const int*   et   = (const int*)d_in[9];
  int n  = in_sizes[0] / IND;
  int E_ = in_sizes[9];
  float* out = (float*)d_out;
  int nbuck = (n + 127) >> 7;

  char* w = (char*)d_ws;
  auto alloc = [&](size_t bytes) {
    char* p = w;
    w += (bytes + 255) & ~(size_t)255;
    return p;
  };
  unsigned short* vb    = (unsigned short*)alloc((size_t)n * HD * 2);
  unsigned short* aggb  = (unsigned short*)alloc((size_t)n * HD * 2);
  unsigned short* nqb   = (unsigned short*)alloc((size_t)n * 16 * 2);
  float* skb      = (float*)alloc((size_t)n * 4 * 4);
  unsigned short* Wallt = (unsigned short*)alloc(160 * 128 * 2);
  unsigned short* Woutt = (unsigned short*)alloc(128 * 128 * 2);
  unsigned int* ebuf = (unsigned int*)alloc((size_t)nbuck * CAP * 4);
  int*   gbuck    = (int*)alloc((size_t)nbuck * 4);

  k0b_pack<<<289, 128, 0, stream>>>(Wq, Wk, attn, ee, Wv, Wout, Wallt, Woutt,
                                    gbuck, nbuck);
  int nblk1 = (n + 63) / 64;
  int nbb = 64;
  int per = (E_ + nbb - 1) / nbb;
  k1b<<<nbb + nblk1, 256, 40960, stream>>>(x, (const uint4*)Wallt, vb, nqb, skb,
                                           n, nbb, ei, et, gbuck, ebuf,
                                           E_, nbuck, per);
  k3f<<<nbuck * 2, 256, 0, stream>>>(ebuf, gbuck, nqb, skb, vb, aggb, n);
  k4_gemm<<<(n + 63)/64, 256, 0, stream>>>(aggb, (const uint4*)Woutt, bout, out, n);
}

// Round 21
// 94.729 us; speedup vs baseline: 1.1956x; 1.1956x over previous
//
#include <hip/hip_runtime.h>
#include <hip/hip_bf16.h>

#define H_   4
#define D_   32
#define HD   128   // H*D
#define IND  128
#define OUTD 128
#define NET  3
#define NEG  0.2f
#define CAP  2048  // bucket capacity (expected ~819 edges/bucket, P(>2048) ~ 0)

typedef short short8 __attribute__((ext_vector_type(8)));
typedef float f32x4  __attribute__((ext_vector_type(4)));

#define AS_GLOBAL(p) ((const __attribute__((address_space(1))) unsigned int*)(p))
#define AS_LDS(p)    ((__attribute__((address_space(3))) unsigned int*)(p))

__device__ __forceinline__ unsigned short f2bf(float f) {
  union { __hip_bfloat16 b; unsigned short u; } x;
  x.b = __float2bfloat16(f);
  return x.u;
}

__device__ __forceinline__ short8 pack_bf8(float4 lo, float4 hi) {
  union { short8 s; unsigned short u[8]; } r;
  r.u[0] = f2bf(lo.x); r.u[1] = f2bf(lo.y); r.u[2] = f2bf(lo.z); r.u[3] = f2bf(lo.w);
  r.u[4] = f2bf(hi.x); r.u[5] = f2bf(hi.y); r.u[6] = f2bf(hi.z); r.u[7] = f2bf(hi.w);
  return r.s;
}

#define BFLO(x) __uint_as_float((x) << 16)
#define BFHI(x) __uint_as_float((x) & 0xFFFF0000u)

// ---------------- K0b: pre-swizzled bf16 weight panels + inline Wred + gbuck zero ----------------
__global__ void k0b_pack(const float* __restrict__ Wq, const float* __restrict__ Wk,
                         const float* __restrict__ attn, const float* __restrict__ ee,
                         const float* __restrict__ Wv, const float* __restrict__ Wout,
                         unsigned short* __restrict__ Wallt,
                         unsigned short* __restrict__ Woutt,
                         int* __restrict__ gbuck, int nbuck) {
  int b = blockIdx.x, i = threadIdx.x; // i = K index
  if (b == 288) {
    for (int k = i; k < nbuck; k += 128) gbuck[k] = 0;  // replaces hipMemsetAsync
    return;
  }
  if (b < 160) {
    int c = b;
    float val = 0.f;
    if (c < 128) {
      val = Wv[i*HD + c];
    } else {
      int cc = c - 128;
      if (cc < 4) {                      // sq(h)
        int h = cc;
        for (int d = 0; d < D_; d++) val += Wq[i*HD + h*D_ + d] * attn[h*2*D_ + d];
      } else if (cc < 16) {              // qe(t,h)
        int t2 = (cc - 4) >> 2, h = (cc - 4) & 3;
        for (int d = 0; d < D_; d++) val += Wq[i*HD + h*D_ + d] * ee[t2*HD + h*D_ + d];
      } else if (cc < 20) {              // sk(h)
        int h = cc - 16;
        for (int d = 0; d < D_; d++) val += Wk[i*HD + h*D_ + d] * attn[h*2*D_ + D_ + d];
      }
    }
    Wallt[(c*128 + i) ^ ((c & 7) << 3)] = f2bf(val);
  } else {
    int c = b - 160;
    Woutt[(c*128 + i) ^ ((c & 7) << 3)] = f2bf(Wout[i*OUTD + c]);
  }
}

// ---------------- K1B: grid-split kernel — bucket blocks FIRST (nbb=256), then GEMM ----------------
// blocks [0, nbb): edge bucketing by dst>>7 (LDS-privatized counters); scatter long-pole
//   starts at t=0 and overlaps the GEMM wave.  nbb=256 is the measured optimum
//   (1024 breaks LDS privatization, 64 is per-block latency-bound).
// blocks [nbb, nbb+nblk1): MFMA GEMM x(n,128) @ [Wv|Wred](128,160); B panel async-
//   staged into 40KB dyn LDS via global_load_lds (16B, linear dest); A global->VGPR.
__global__ __launch_bounds__(256) void k1b(const float* __restrict__ x,
    const uint4* __restrict__ Wallt,
    unsigned short* __restrict__ vb, unsigned short* __restrict__ nqb,
    float* __restrict__ skb, int n, int nbb,
    const int* __restrict__ ei, const int* __restrict__ et,
    int* __restrict__ gbuck, unsigned int* __restrict__ ebuf,
    int E_, int nbuck, int per) {
  extern __shared__ char dlds[];
  int t = threadIdx.x;
  if (blockIdx.x < nbb) {
    // ---- bucket part ----
    int* cnt  = (int*)dlds;
    int* base = cnt + 1024;
    for (int i = t; i < nbuck; i += 256) cnt[i] = 0;
    __syncthreads();
    int bb = blockIdx.x;
    int e0 = bb * per;
    int e1 = min(e0 + per, E_);
    for (int e = e0 + t; e < e1; e += 256)
      atomicAdd(&cnt[ei[E_ + e] >> 7], 1);
    __syncthreads();
    for (int i = t; i < nbuck; i += 256) {
      int c = cnt[i];
      base[i] = c ? atomicAdd(&gbuck[i], c) : 0;
      cnt[i] = 0;
    }
    __syncthreads();
    for (int e = e0 + t; e < e1; e += 256) {
      int d = ei[E_ + e];
      int b = d >> 7;
      int pos = base[b] + atomicAdd(&cnt[b], 1);
      ebuf[(size_t)b * CAP + pos] =
          (unsigned)ei[e] | ((unsigned)et[e] << 17) | ((unsigned)(d & 127) << 19);
    }
    return;
  }
  // ---- GEMM part ----
  uint4* ldsB = (uint4*)dlds;
  int wv = t >> 6, lane = t & 63;
  int l15 = lane & 15, l16 = lane >> 4;
  int base = (blockIdx.x - nbb) * 64;
  int arow = base + wv*16 + l15;
  int rr = min(arow, n - 1);
  const float* xr = &x[(size_t)rr*IND + l16*8];
  float4 lo[4], hi[4];
  #pragma unroll
  for (int kk = 0; kk < 4; kk++) {
    lo[kk] = *(const float4*)(xr + kk*32);
    hi[kk] = *(const float4*)(xr + kk*32 + 4);
  }
  #pragma unroll
  for (int i = 0; i < 10; i++) {
    const uint4* gp = Wallt + i*256 + wv*64 + lane;
    uint4* lp = (uint4*)dlds + i*256 + wv*64;  // wave-uniform; HW adds lane*16
    __builtin_amdgcn_global_load_lds(AS_GLOBAL(gp), AS_LDS(lp), 16, 0, 0);
  }
  short8 afr[4];
  #pragma unroll
  for (int kk = 0; kk < 4; kk++) afr[kk] = pack_bf8(lo[kk], hi[kk]);
  __syncthreads();
  f32x4 acc[10];
  #pragma unroll
  for (int nt = 0; nt < 10; nt++) acc[nt] = (f32x4){0.f, 0.f, 0.f, 0.f};
  #pragma unroll
  for (int nt = 0; nt < 10; nt++) {
    int bcol = nt*16 + l15;
    #pragma unroll
    for (int kk = 0; kk < 4; kk++) {
      int bytec = kk*64 + l16*16;
      short8 b = *(const short8*)((const char*)ldsB + ((bcol*256 + bytec) ^ ((bcol & 7) << 4)));
      acc[nt] = __builtin_amdgcn_mfma_f32_16x16x32_bf16(afr[kk], b, acc[nt], 0, 0, 0);
    }
  }
  int rowbase = base + wv*16 + l16*4;
  #pragma unroll
  for (int nt = 0; nt < 10; nt++) {
    int col = nt*16 + l15;
    #pragma unroll
    for (int r = 0; r < 4; r++) {
      int row = rowbase + r;
      if (row >= n) continue;
      float val = acc[nt][r];
      if (nt < 8)       vb[(size_t)row*HD + col] = f2bf(val);
      else if (nt == 8) nqb[((size_t)row << 4) + (col - 128)] = f2bf(val);
      else { int c = col - 144; if (c < 4) skb[(size_t)row*4 + c] = val; }
    }
  }
}

// ---------------- K3F: fused per-bucket counting sort (LDS) + softmax-aggregation ----------------
// TWO blocks per bucket (measured-best): both sort the full bucket into LDS;
// each block gathers 64 of the 128 dsts.
__global__ __launch_bounds__(256) void k3f(const unsigned int* __restrict__ ebuf,
    const int* __restrict__ gbuck,
    const unsigned short* __restrict__ nqb, const float* __restrict__ skb,
    const unsigned short* __restrict__ vb, unsigned short* __restrict__ aggb, int n) {
  __shared__ unsigned int el[CAP];     // 8KB sorted edge words
  __shared__ int cnt[128], cur[128], sc[128];
  __shared__ float s_esc[16][17][4];
  __shared__ int s_src[16][17];
  int b = blockIdx.x >> 1;
  int half = blockIdx.x & 1;
  int t = threadIdx.x;
  int m = gbuck[b];
  if (t < 128) cnt[t] = 0;
  __syncthreads();
  const unsigned int* eb = ebuf + (size_t)b * CAP;
  for (int i = t; i < m; i += 256)
    atomicAdd(&cnt[(eb[i] >> 19) & 127], 1);
  __syncthreads();
  if (t < 128) sc[t] = cnt[t];
  __syncthreads();
  for (int off = 1; off < 128; off <<= 1) {
    int v = (t >= off && t < 128) ? sc[t - off] : 0;
    __syncthreads();
    if (t < 128) sc[t] += v;
    __syncthreads();
  }
  if (t < 128) cur[t] = sc[t] - cnt[t];
  __syncthreads();
  for (int i = t; i < m; i += 256) {
    unsigned int w = eb[i];
    int dl = (w >> 19) & 127;
    el[atomicAdd(&cur[dl], 1)] = w;
  }
  __syncthreads();
  // ---- gather phase: group g handles dsts dl = half*64 + g*4 .. +3 ----
  int g = t >> 4, s = t & 15;
  int h = s >> 2;
  for (int k = 0; k < 4; k++) {
    int dl = half*64 + g*4 + k;
    int dst = b*128 + dl;
    if (dst >= n) continue;
    int deg = cnt[dl];
    unsigned short* orow = &aggb[(size_t)dst*HD + s*8];
    if (deg == 0) {
      *(uint4*)orow = make_uint4(0u, 0u, 0u, 0u);
      continue;
    }
    int off0 = sc[dl] - deg;
    float4 sk4 = *(const float4*)(&skb[(size_t)dst*4]);
    float dp0 = 0.f, dp1 = 0.f, dp2 = 0.f, dp3 = 0.f;
    float a0=0.f,a1=0.f,a2=0.f,a3=0.f,a4=0.f,a5=0.f,a6=0.f,a7=0.f;
    for (int bas = 0; bas < deg; bas += 16) {
      int cnt2 = min(16, deg - bas);
      float e0 = 0.f, e1 = 0.f, e2 = 0.f, e3 = 0.f;
      int srcoff = 0;
      if (s < cnt2) {
        unsigned int p = el[off0 + bas + s];
        int src = p & 0x1FFFF;
        int ety = (p >> 17) & 3;
        const unsigned short* nr = nqb + ((size_t)src << 4);
        uint2 sqp = *(const uint2*)nr;                 // sq[0..3] bf16
        uint2 qep = *(const uint2*)(nr + 4 + ety*4);   // qe[ety][0..3] bf16
        float s0 = BFLO(sqp.x) + sk4.x;
        float s1 = BFHI(sqp.x) + sk4.y;
        float s2 = BFLO(sqp.y) + sk4.z;
        float s3 = BFHI(sqp.y) + sk4.w;
        s0 = (s0 >= 0.f ? s0 : NEG*s0) + BFLO(qep.x); e0 = __expf(s0);
        s1 = (s1 >= 0.f ? s1 : NEG*s1) + BFHI(qep.x); e1 = __expf(s1);
        s2 = (s2 >= 0.f ? s2 : NEG*s2) + BFLO(qep.y); e2 = __expf(s2);
        s3 = (s3 >= 0.f ? s3 : NEG*s3) + BFHI(qep.y); e3 = __expf(s3);
        dp0 += e0; dp1 += e1; dp2 += e2; dp3 += e3;
        srcoff = src << 7;             // src*HD
      }
      s_src[g][s] = srcoff;
      *(float4*)(&s_esc[g][s][0]) = make_float4(e0, e1, e2, e3);
      __builtin_amdgcn_wave_barrier();
      int e = 0;
      for (; e + 4 <= cnt2; e += 4) {    // 4 gathers in flight per lane
        float al0 = s_esc[g][e+0][h], al1 = s_esc[g][e+1][h];
        float al2 = s_esc[g][e+2][h], al3 = s_esc[g][e+3][h];
        const unsigned short* p0 = vb + s_src[g][e+0] + s*8;
        const unsigned short* p1 = vb + s_src[g][e+1] + s*8;
        const unsigned short* p2 = vb + s_src[g][e+2] + s*8;
        const unsigned short* p3 = vb + s_src[g][e+3] + s*8;
        uint4 v0 = *(const uint4*)p0;
        uint4 v1 = *(const uint4*)p1;
        uint4 v2 = *(const uint4*)p2;
        uint4 v3 = *(const uint4*)p3;
        a0 += al0 * BFLO(v0.x); a1 += al0 * BFHI(v0.x);
        a2 += al0 * BFLO(v0.y); a3 += al0 * BFHI(v0.y);
        a4 += al0 * BFLO(v0.z); a5 += al0 * BFHI(v0.z);
        a6 += al0 * BFLO(v0.w); a7 += al0 * BFHI(v0.w);
        a0 += al1 * BFLO(v1.x); a1 += al1 * BFHI(v1.x);
        a2 += al1 * BFLO(v1.y); a3 += al1 * BFHI(v1.y);
        a4 += al1 * BFLO(v1.z); a5 += al1 * BFHI(v1.z);
        a6 += al1 * BFLO(v1.w); a7 += al1 * BFHI(v1.w);
        a0 += al2 * BFLO(v2.x); a1 += al2 * BFHI(v2.x);
        a2 += al2 * BFLO(v2.y); a3 += al2 * BFHI(v2.y);
        a4 += al2 * BFLO(v2.z); a5 += al2 * BFHI(v2.z);
        a6 += al2 * BFLO(v2.w); a7 += al2 * BFHI(v2.w);
        a0 += al3 * BFLO(v3.x); a1 += al3 * BFHI(v3.x);
        a2 += al3 * BFLO(v3.y); a3 += al3 * BFHI(v3.y);
        a4 += al3 * BFLO(v3.z); a5 += al3 * BFHI(v3.z);
        a6 += al3 * BFLO(v3.w); a7 += al3 * BFHI(v3.w);
      }
      for (; e < cnt2; e++) {
        float a = s_esc[g][e][h];
        const unsigned short* p = vb + s_src[g][e] + s*8;
        uint4 vv = *(const uint4*)p;
        a0 += a * BFLO(vv.x); a1 += a * BFHI(vv.x);
        a2 += a * BFLO(vv.y); a3 += a * BFHI(vv.y);
        a4 += a * BFLO(vv.z); a5 += a * BFHI(vv.z);
        a6 += a * BFLO(vv.w); a7 += a * BFHI(vv.w);
      }
      __builtin_amdgcn_wave_barrier();
    }
    #pragma unroll
    for (int off = 1; off < 16; off <<= 1) {
      dp0 += __shfl_xor(dp0, off);
      dp1 += __shfl_xor(dp1, off);
      dp2 += __shfl_xor(dp2, off);
      dp3 += __shfl_xor(dp3, off);
    }
    float den = (h == 0) ? dp0 : (h == 1) ? dp1 : (h == 2) ? dp2 : dp3;
    float inv = 1.f / (den + 1e-10f);
    uint4 pk;
    pk.x = (unsigned)f2bf(a0*inv) | ((unsigned)f2bf(a1*inv) << 16);
    pk.y = (unsigned)f2bf(a2*inv) | ((unsigned)f2bf(a3*inv) << 16);
    pk.z = (unsigned)f2bf(a4*inv) | ((unsigned)f2bf(a5*inv) << 16);
    pk.w = (unsigned)f2bf(a6*inv) | ((unsigned)f2bf(a7*inv) << 16);
    *(uint4*)orow = pk;
  }
}

// ---------------- K4: MFMA GEMM  out = aggb @ Wout + bout ----------------
__global__ __launch_bounds__(256) void k4_gemm(const unsigned short* __restrict__ aggb,
    const uint4* __restrict__ Woutt, const float* __restrict__ bout,
    float* __restrict__ out, int n) {
  __shared__ uint4 ldsB[2048]; // 32KB
  int t = threadIdx.x;
  #pragma unroll
  for (int i = 0; i < 8; i++) ldsB[i*256 + t] = Woutt[i*256 + t];
  int wv = t >> 6, lane = t & 63;
  int l15 = lane & 15, l16 = lane >> 4;
  int base = blockIdx.x * 64;
  int arow = base + wv*16 + l15;
  int rr = min(arow, n - 1);
  const unsigned short* ar = &aggb[(size_t)rr*HD + l16*8];
  short8 afr[4];
  #pragma unroll
  for (int kk = 0; kk < 4; kk++)
    afr[kk] = *(const short8*)(ar + kk*32);
  __syncthreads();
  f32x4 acc[8];
  #pragma unroll
  for (int nt = 0; nt < 8; nt++) acc[nt] = (f32x4){0.f, 0.f, 0.f, 0.f};
  #pragma unroll
  for (int nt = 0; nt < 8; nt++) {
    int bcol = nt*16 + l15;
    #pragma unroll
    for (int kk = 0; kk < 4; kk++) {
      int bytec = kk*64 + l16*16;
      short8 b = *(const short8*)((const char*)ldsB + ((bcol*256 + bytec) ^ ((bcol & 7) << 4)));
      acc[nt] = __builtin_amdgcn_mfma_f32_16x16x32_bf16(afr[kk], b, acc[nt], 0, 0, 0);
    }
  }
  int rowbase = base + wv*16 + l16*4;
  #pragma unroll
  for (int nt = 0; nt < 8; nt++) {
    int col = nt*16 + l15;
    float bv = bout[col];
    #pragma unroll
    for (int r = 0; r < 4; r++) {
      int row = rowbase + r;
      if (row < n) out[(size_t)row*OUTD + col] = acc[nt][r] + bv;
    }
  }
}

extern "C" void kernel_launch(void* const* d_in, const int* in_sizes, int n_in,
                              void* d_out, int out_size, void* d_ws, size_t ws_size,
                              hipStream_t stream) {
  const float* x    = (const float*)d_in[0];
  const float* Wq   = (const float*)d_in[1];
  const float* Wk   = (const float*)d_in[2];
  const float* Wv   = (const float*)d_in[3];
  const float* attn = (const float*)d_in[4];
  const float* ee   = (const float*)d_in[5];
  const float* Wout = (const float*)d_in[6];
  const float* bout = (const float*)d_in[7];
  const int*   ei   = (const int*)d_in[8];
  const int*   et   = (const int*)d_in[9];
  int n  = in_sizes[0] / IND;
  int E_ = in_sizes[9];
  float* out = (float*)d_out;
  int nbuck = (n + 127) >> 7;

  char* w = (char*)d_ws;
  auto alloc = [&](size_t bytes) {
    char* p = w;
    w += (bytes + 255) & ~(size_t)255;
    return p;
  };
  unsigned short* vb    = (unsigned short*)alloc((size_t)n * HD * 2);
  unsigned short* aggb  = (unsigned short*)alloc((size_t)n * HD * 2);
  unsigned short* nqb   = (unsigned short*)alloc((size_t)n * 16 * 2);
  float* skb      = (float*)alloc((size_t)n * 4 * 4);
  unsigned short* Wallt = (unsigned short*)alloc(160 * 128 * 2);
  unsigned short* Woutt = (unsigned short*)alloc(128 * 128 * 2);
  unsigned int* ebuf = (unsigned int*)alloc((size_t)nbuck * CAP * 4);
  int*   gbuck    = (int*)alloc((size_t)nbuck * 4);

  k0b_pack<<<289, 128, 0, stream>>>(Wq, Wk, attn, ee, Wv, Wout, Wallt, Woutt,
                                    gbuck, nbuck);
  int nblk1 = (n + 63) / 64;
  int nbb = 256;
  int per = (E_ + nbb - 1) / nbb;
  k1b<<<nbb + nblk1, 256, 40960, stream>>>(x, (const uint4*)Wallt, vb, nqb, skb,
                                           n, nbb, ei, et, gbuck, ebuf,
                                           E_, nbuck, per);
  k3f<<<nbuck * 2, 256, 0, stream>>>(ebuf, gbuck, nqb, skb, vb, aggb, n);
  k4_gemm<<<(n + 63)/64, 256, 0, stream>>>(aggb, (const uint4*)Woutt, bout, out, n);
}